// Round 1
// baseline (2329.061 us; speedup 1.0000x reference)
//
#include <hip/hip_runtime.h>
#include <hip/hip_bf16.h>
#include <cstdint>

#define NN 50000
#define NE 1200000
#define DD 128
#define RR 6
#define NEG 0.2f

typedef __hip_bfloat16 bf16;

// ---------------- init: out = x + bias, segmax = key(-inf), segsum = 0 ----
__global__ __launch_bounds__(256) void k_init(const float* __restrict__ x,
    const float* __restrict__ bias, float* __restrict__ out,
    unsigned* __restrict__ segmax, float* __restrict__ segsum) {
  int idx = blockIdx.x * 256 + threadIdx.x;
  if (idx < NN * DD) out[idx] = x[idx] + bias[idx & (DD - 1)];
  if (idx < NN) { segmax[idx] = 0x007FFFFFu; segsum[idx] = 0.0f; }
}

// ---------------- wq[r,d] = sum_o W[r,d,o] q[o]; same for k ---------------
__global__ __launch_bounds__(256) void k_wqk(const float* __restrict__ W,
    const float* __restrict__ qv, const float* __restrict__ kv,
    float* __restrict__ wq, float* __restrict__ wk) {
  int t = blockIdx.x * 256 + threadIdx.x;
  if (t >= RR * DD) return;
  int r = t / DD, d = t % DD;
  const float* row = W + ((size_t)r * DD + d) * DD;
  float aq = 0.f, ak = 0.f;
  for (int o = 0; o < DD; ++o) { float w = row[o]; aq += w * qv[o]; ak += w * kv[o]; }
  wq[t] = aq; wk[t] = ak;
}

// ---------------- nq[r,n] = x[n]·wq[r], one wave per node -----------------
__global__ __launch_bounds__(256) void k_nqk(const float* __restrict__ x,
    const float* __restrict__ wq, const float* __restrict__ wk,
    float* __restrict__ nq, float* __restrict__ nk) {
  int w = threadIdx.x >> 6, lane = threadIdx.x & 63;
  int n = blockIdx.x * 4 + w;
  if (n >= NN) return;
  float x0 = x[(size_t)n * DD + lane];
  float x1 = x[(size_t)n * DD + 64 + lane];
  for (int r = 0; r < RR; ++r) {
    float pq = x0 * wq[r * DD + lane] + x1 * wq[r * DD + 64 + lane];
    float pk = x0 * wk[r * DD + lane] + x1 * wk[r * DD + 64 + lane];
    #pragma unroll
    for (int m = 32; m > 0; m >>= 1) { pq += __shfl_xor(pq, m); pk += __shfl_xor(pk, m); }
    if (lane == 0) { nq[r * NN + n] = pq; nk[r * NN + n] = pk; }
  }
}

// ---------------- hx[r,n,o] = sum_d x[n,d] W[r,d,o]  (bf16 out) -----------
#define BM 64
#define KB 32
__global__ __launch_bounds__(256) void k_gemm(const float* __restrict__ x,
    const float* __restrict__ W, bf16* __restrict__ hx) {
  __shared__ float sx[BM][KB + 4];   // padded: 64x36
  __shared__ float sw[KB][DD + 4];   // padded: 32x132
  int r = blockIdx.y;
  int row0 = blockIdx.x * BM;
  int tid = threadIdx.x;
  int ty = tid >> 4, tx = tid & 15;   // 16x16 threads, each 4 rows x 8 cols
  const float* Wr = W + (size_t)r * DD * DD;
  float acc[4][8];
  #pragma unroll
  for (int i = 0; i < 4; ++i)
    #pragma unroll
    for (int c = 0; c < 8; ++c) acc[i][c] = 0.f;

  for (int k0 = 0; k0 < DD; k0 += KB) {
    // stage x tile [64][32]: each thread 8 consecutive floats
    {
      int idx = tid * 8;
      int xr = idx >> 5, xc = idx & 31;
      int grow = row0 + xr;
      float4 v0 = make_float4(0.f, 0.f, 0.f, 0.f), v1 = v0;
      if (grow < NN) {
        const float4* src = reinterpret_cast<const float4*>(x + (size_t)grow * DD + k0 + xc);
        v0 = src[0]; v1 = src[1];
      }
      *reinterpret_cast<float4*>(&sx[xr][xc]) = v0;
      *reinterpret_cast<float4*>(&sx[xr][xc + 4]) = v1;
    }
    // stage W tile [32][128]: each thread 16 consecutive floats
    {
      int wr = tid >> 3, wc = (tid & 7) * 16;
      const float4* src = reinterpret_cast<const float4*>(Wr + (size_t)(k0 + wr) * DD + wc);
      float4* dst = reinterpret_cast<float4*>(&sw[wr][wc]);
      dst[0] = src[0]; dst[1] = src[1]; dst[2] = src[2]; dst[3] = src[3];
    }
    __syncthreads();
    #pragma unroll
    for (int kk = 0; kk < KB; kk += 4) {
      float4 a[4];
      #pragma unroll
      for (int i = 0; i < 4; ++i)
        a[i] = *reinterpret_cast<const float4*>(&sx[ty * 4 + i][kk]);
      #pragma unroll
      for (int j = 0; j < 4; ++j) {
        float4 b0 = *reinterpret_cast<const float4*>(&sw[kk + j][tx * 8]);
        float4 b1 = *reinterpret_cast<const float4*>(&sw[kk + j][tx * 8 + 4]);
        #pragma unroll
        for (int i = 0; i < 4; ++i) {
          float av = (&a[i].x)[j];
          acc[i][0] += av * b0.x; acc[i][1] += av * b0.y;
          acc[i][2] += av * b0.z; acc[i][3] += av * b0.w;
          acc[i][4] += av * b1.x; acc[i][5] += av * b1.y;
          acc[i][6] += av * b1.z; acc[i][7] += av * b1.w;
        }
      }
    }
    __syncthreads();
  }
  // write bf16 hx
  #pragma unroll
  for (int i = 0; i < 4; ++i) {
    int rr = row0 + ty * 4 + i;
    if (rr >= NN) continue;
    bf16 tmp[8];
    #pragma unroll
    for (int c = 0; c < 8; ++c) tmp[c] = __float2bfloat16(acc[i][c]);
    *reinterpret_cast<uint4*>(hx + ((size_t)r * NN + rr) * DD + tx * 8) =
        *reinterpret_cast<const uint4*>(tmp);
  }
}

// ---------------- edge pass 1: logits + atomic segment max ---------------
__global__ __launch_bounds__(256) void k_logits(const int* __restrict__ ei,
    const int* __restrict__ et, const float* __restrict__ nq,
    const float* __restrict__ nk, float* __restrict__ alpha,
    unsigned* __restrict__ segmax) {
  int e = blockIdx.x * 256 + threadIdx.x;
  if (e >= NE) return;
  int s = ei[e], d = ei[NE + e], r = et[e];
  float l = nq[r * NN + d] + nk[r * NN + s];
  l = l > 0.f ? l : NEG * l;
  alpha[e] = l;
  unsigned key = __float_as_uint(l);
  key = (key & 0x80000000u) ? ~key : (key | 0x80000000u);
  atomicMax(&segmax[d], key);
}

// ---------------- edge pass 2: e = exp(l - m), atomic segment sum --------
__global__ __launch_bounds__(256) void k_exp(const int* __restrict__ ei,
    float* __restrict__ alpha, const unsigned* __restrict__ segmax,
    float* __restrict__ segsum) {
  int e = blockIdx.x * 256 + threadIdx.x;
  if (e >= NE) return;
  int d = ei[NE + e];
  unsigned mk = segmax[d];
  float m = (mk & 0x80000000u) ? __uint_as_float(mk ^ 0x80000000u)
                               : __uint_as_float(~mk);
  float ev = expf(alpha[e] - m);
  alpha[e] = ev;
  atomicAdd(&segsum[d], ev);
}

// ---------------- edge pass 3: alpha, gather hx row, scatter-add ----------
__global__ __launch_bounds__(256) void k_scatter(const int* __restrict__ ei,
    const int* __restrict__ et, const bf16* __restrict__ hx,
    const float* __restrict__ segsum, float* __restrict__ alpha,
    float* __restrict__ out) {
  int g = threadIdx.x >> 5, lane = threadIdx.x & 31;
  int e = blockIdx.x * 8 + g;
  if (e >= NE) return;
  int s = ei[e], d = ei[NE + e], r = et[e];
  float ev = alpha[e];
  float a = ev / (segsum[d] + 1e-16f);
  if (lane == 0) alpha[e] = a;
  const bf16* row = hx + ((size_t)r * NN + s) * DD;
  int c0 = lane * 4;
  uint2 pk = *reinterpret_cast<const uint2*>(row + c0);
  float v0 = __uint_as_float((pk.x & 0xFFFFu) << 16);
  float v1 = __uint_as_float(pk.x & 0xFFFF0000u);
  float v2 = __uint_as_float((pk.y & 0xFFFFu) << 16);
  float v3 = __uint_as_float(pk.y & 0xFFFF0000u);
  float* o = out + (size_t)d * DD + c0;
  atomicAdd(o + 0, a * v0);
  atomicAdd(o + 1, a * v1);
  atomicAdd(o + 2, a * v2);
  atomicAdd(o + 3, a * v3);
}

extern "C" void kernel_launch(void* const* d_in, const int* in_sizes, int n_in,
                              void* d_out, int out_size, void* d_ws, size_t ws_size,
                              hipStream_t stream) {
  const float* x   = (const float*)d_in[0];
  const int*   ei  = (const int*)d_in[1];
  const int*   et  = (const int*)d_in[2];
  const float* W   = (const float*)d_in[3];
  const float* qv  = (const float*)d_in[4];
  const float* kv  = (const float*)d_in[5];
  const float* bias= (const float*)d_in[6];

  float* out   = (float*)d_out;              // [NN*DD]
  float* alpha = out + (size_t)NN * DD;      // [NE]

  bf16*  hx     = (bf16*)d_ws;                         // RR*NN*DD bf16 = 76.8 MB
  float* nq     = (float*)(hx + (size_t)RR * NN * DD); // RR*NN
  float* nk     = nq + (size_t)RR * NN;
  float* wq     = nk + (size_t)RR * NN;                // RR*DD
  float* wk     = wq + RR * DD;
  unsigned* segmax = (unsigned*)(wk + RR * DD);        // NN
  float* segsum = (float*)(segmax + NN);               // NN

  k_init<<<(NN * DD + 255) / 256, 256, 0, stream>>>(x, bias, out, segmax, segsum);
  k_wqk<<<(RR * DD + 255) / 256, 256, 0, stream>>>(W, qv, kv, wq, wk);
  k_gemm<<<dim3((NN + BM - 1) / BM, RR), 256, 0, stream>>>(x, W, hx);
  k_nqk<<<(NN + 3) / 4, 256, 0, stream>>>(x, wq, wk, nq, nk);
  k_logits<<<(NE + 255) / 256, 256, 0, stream>>>(ei, et, nq, nk, alpha, segmax);
  k_exp<<<(NE + 255) / 256, 256, 0, stream>>>(ei, alpha, segmax, segsum);
  k_scatter<<<(NE + 7) / 8, 256, 0, stream>>>(ei, et, hx, segsum, alpha, out);
}

// Round 2
// 447.758 us; speedup vs baseline: 5.2016x; 5.2016x over previous
//
#include <hip/hip_runtime.h>
#include <hip/hip_bf16.h>
#include <cstdint>

#define NN 50000
#define NE 1200000
#define DD 128
#define RR 6
#define NEG 0.2f

typedef __hip_bfloat16 bf16;

__device__ __forceinline__ float bflo(unsigned u) { return __uint_as_float((u & 0xFFFFu) << 16); }
__device__ __forceinline__ float bfhi(unsigned u) { return __uint_as_float(u & 0xFFFF0000u); }

// ---------------- init: zero degree + cursor ------------------------------
__global__ __launch_bounds__(256) void k_init(int* __restrict__ deg,
                                              int* __restrict__ cur) {
  int idx = blockIdx.x * 256 + threadIdx.x;
  if (idx < NN) { deg[idx] = 0; cur[idx] = 0; }
}

// ---------------- wq[r,d] = sum_o W[r,d,o] q[o]; same for k ---------------
__global__ __launch_bounds__(256) void k_wqk(const float* __restrict__ W,
    const float* __restrict__ qv, const float* __restrict__ kv,
    float* __restrict__ wq, float* __restrict__ wk) {
  int t = blockIdx.x * 256 + threadIdx.x;
  if (t >= RR * DD) return;
  int r = t / DD, d = t % DD;
  const float* row = W + ((size_t)r * DD + d) * DD;
  float aq = 0.f, ak = 0.f;
  for (int o = 0; o < DD; ++o) { float w = row[o]; aq += w * qv[o]; ak += w * kv[o]; }
  wq[t] = aq; wk[t] = ak;
}

// ---------------- nq[r,n] = x[n]·wq[r], one wave per node -----------------
__global__ __launch_bounds__(256) void k_nqk(const float* __restrict__ x,
    const float* __restrict__ wq, const float* __restrict__ wk,
    float* __restrict__ nq, float* __restrict__ nk) {
  int w = threadIdx.x >> 6, lane = threadIdx.x & 63;
  int n = blockIdx.x * 4 + w;
  if (n >= NN) return;
  float x0 = x[(size_t)n * DD + lane];
  float x1 = x[(size_t)n * DD + 64 + lane];
  for (int r = 0; r < RR; ++r) {
    float pq = x0 * wq[r * DD + lane] + x1 * wq[r * DD + 64 + lane];
    float pk = x0 * wk[r * DD + lane] + x1 * wk[r * DD + 64 + lane];
    #pragma unroll
    for (int m = 32; m > 0; m >>= 1) { pq += __shfl_xor(pq, m); pk += __shfl_xor(pk, m); }
    if (lane == 0) { nq[r * NN + n] = pq; nk[r * NN + n] = pk; }
  }
}

// ---------------- hx[r,n,o] = sum_d x[n,d] W[r,d,o]  (bf16 out) -----------
#define BM 64
#define KB 32
__global__ __launch_bounds__(256) void k_gemm(const float* __restrict__ x,
    const float* __restrict__ W, bf16* __restrict__ hx) {
  __shared__ float sx[BM][KB + 4];
  __shared__ float sw[KB][DD + 4];
  int r = blockIdx.y;
  int row0 = blockIdx.x * BM;
  int tid = threadIdx.x;
  int ty = tid >> 4, tx = tid & 15;
  const float* Wr = W + (size_t)r * DD * DD;
  float acc[4][8];
  #pragma unroll
  for (int i = 0; i < 4; ++i)
    #pragma unroll
    for (int c = 0; c < 8; ++c) acc[i][c] = 0.f;

  for (int k0 = 0; k0 < DD; k0 += KB) {
    {
      int idx = tid * 8;
      int xr = idx >> 5, xc = idx & 31;
      int grow = row0 + xr;
      float4 v0 = make_float4(0.f, 0.f, 0.f, 0.f), v1 = v0;
      if (grow < NN) {
        const float4* src = reinterpret_cast<const float4*>(x + (size_t)grow * DD + k0 + xc);
        v0 = src[0]; v1 = src[1];
      }
      *reinterpret_cast<float4*>(&sx[xr][xc]) = v0;
      *reinterpret_cast<float4*>(&sx[xr][xc + 4]) = v1;
    }
    {
      int wr = tid >> 3, wc = (tid & 7) * 16;
      const float4* src = reinterpret_cast<const float4*>(Wr + (size_t)(k0 + wr) * DD + wc);
      float4* dst = reinterpret_cast<float4*>(&sw[wr][wc]);
      dst[0] = src[0]; dst[1] = src[1]; dst[2] = src[2]; dst[3] = src[3];
    }
    __syncthreads();
    #pragma unroll
    for (int kk = 0; kk < KB; kk += 4) {
      float4 a[4];
      #pragma unroll
      for (int i = 0; i < 4; ++i)
        a[i] = *reinterpret_cast<const float4*>(&sx[ty * 4 + i][kk]);
      #pragma unroll
      for (int j = 0; j < 4; ++j) {
        float4 b0 = *reinterpret_cast<const float4*>(&sw[kk + j][tx * 8]);
        float4 b1 = *reinterpret_cast<const float4*>(&sw[kk + j][tx * 8 + 4]);
        #pragma unroll
        for (int i = 0; i < 4; ++i) {
          float av = (&a[i].x)[j];
          acc[i][0] += av * b0.x; acc[i][1] += av * b0.y;
          acc[i][2] += av * b0.z; acc[i][3] += av * b0.w;
          acc[i][4] += av * b1.x; acc[i][5] += av * b1.y;
          acc[i][6] += av * b1.z; acc[i][7] += av * b1.w;
        }
      }
    }
    __syncthreads();
  }
  #pragma unroll
  for (int i = 0; i < 4; ++i) {
    int rr = row0 + ty * 4 + i;
    if (rr >= NN) continue;
    bf16 tmp[8];
    #pragma unroll
    for (int c = 0; c < 8; ++c) tmp[c] = __float2bfloat16(acc[i][c]);
    *reinterpret_cast<uint4*>(hx + ((size_t)r * NN + rr) * DD + tx * 8) =
        *reinterpret_cast<const uint4*>(tmp);
  }
}

// ---------------- histogram of destinations -------------------------------
__global__ __launch_bounds__(256) void k_hist(const int* __restrict__ ei,
                                              int* __restrict__ deg) {
  int e = blockIdx.x * 256 + threadIdx.x;
  if (e >= NE) return;
  atomicAdd(&deg[ei[NE + e]], 1);
}

// ---------------- exclusive scan (single block) ----------------------------
__global__ __launch_bounds__(1024) void k_scan(const int* __restrict__ deg,
                                               int* __restrict__ offs) {
  __shared__ int part[1024];
  int t = threadIdx.x;
  const int C = (NN + 1023) / 1024;
  int lo = t * C, hi = lo + C < NN ? lo + C : NN;
  int sum = 0;
  for (int i = lo; i < hi; ++i) sum += deg[i];
  part[t] = sum;
  __syncthreads();
  for (int off = 1; off < 1024; off <<= 1) {
    int u = (t >= off) ? part[t - off] : 0;
    __syncthreads();
    part[t] += u;
    __syncthreads();
  }
  int run = part[t] - sum;   // exclusive base for this chunk
  for (int i = lo; i < hi; ++i) { offs[i] = run; run += deg[i]; }
}

// ---------------- place edges into CSR slots, precompute logits ------------
__global__ __launch_bounds__(256) void k_place(const int* __restrict__ ei,
    const int* __restrict__ et, const float* __restrict__ nq,
    const float* __restrict__ nk, const int* __restrict__ offs,
    int* __restrict__ cur, int* __restrict__ rec_src,
    int* __restrict__ rec_eid, float* __restrict__ rec_logit) {
  int e = blockIdx.x * 256 + threadIdx.x;
  if (e >= NE) return;
  int s = ei[e], d = ei[NE + e], r = et[e];
  float l = nq[r * NN + d] + nk[r * NN + s];
  l = l > 0.f ? l : NEG * l;
  int pos = offs[d] + atomicAdd(&cur[d], 1);
  rec_src[pos] = s | (r << 20);
  rec_eid[pos] = e;
  rec_logit[pos] = l;
}

// ---------------- fused online-softmax gather-aggregate --------------------
// one 32-lane group per destination node; 4 output floats per lane
__global__ __launch_bounds__(256) void k_agg(const float* __restrict__ x,
    const float* __restrict__ bias, const int* __restrict__ offs,
    const int* __restrict__ deg, const int* __restrict__ rec_src,
    const int* __restrict__ rec_eid, const float* __restrict__ rec_logit,
    const bf16* __restrict__ hx, float* __restrict__ out,
    float* __restrict__ alpha) {
  int g = threadIdx.x >> 5, lane = threadIdx.x & 31;
  int n = blockIdx.x * 8 + g;
  if (n >= NN) return;
  int base = offs[n], cnt = deg[n];

  float m = -1e30f, ssum = 0.f;
  float a0 = 0.f, a1 = 0.f, a2 = 0.f, a3 = 0.f;

  int j = 0;
  for (; j + 1 < cnt; j += 2) {
    int sr1 = rec_src[base + j], sr2 = rec_src[base + j + 1];
    float l1 = rec_logit[base + j], l2 = rec_logit[base + j + 1];
    const bf16* row1 = hx + ((size_t)(sr1 >> 20) * NN + (sr1 & 0xFFFFF)) * DD + lane * 4;
    const bf16* row2 = hx + ((size_t)(sr2 >> 20) * NN + (sr2 & 0xFFFFF)) * DD + lane * 4;
    uint2 q1 = *reinterpret_cast<const uint2*>(row1);
    uint2 q2 = *reinterpret_cast<const uint2*>(row2);
    float mn = fmaxf(m, fmaxf(l1, l2));
    float sc = __expf(m - mn);
    float p1 = __expf(l1 - mn), p2 = __expf(l2 - mn);
    ssum = ssum * sc + p1 + p2;
    a0 = a0 * sc + p1 * bflo(q1.x) + p2 * bflo(q2.x);
    a1 = a1 * sc + p1 * bfhi(q1.x) + p2 * bfhi(q2.x);
    a2 = a2 * sc + p1 * bflo(q1.y) + p2 * bflo(q2.y);
    a3 = a3 * sc + p1 * bfhi(q1.y) + p2 * bfhi(q2.y);
    m = mn;
  }
  if (j < cnt) {
    int sr1 = rec_src[base + j];
    float l1 = rec_logit[base + j];
    const bf16* row1 = hx + ((size_t)(sr1 >> 20) * NN + (sr1 & 0xFFFFF)) * DD + lane * 4;
    uint2 q1 = *reinterpret_cast<const uint2*>(row1);
    float mn = fmaxf(m, l1);
    float sc = __expf(m - mn);
    float p1 = __expf(l1 - mn);
    ssum = ssum * sc + p1;
    a0 = a0 * sc + p1 * bflo(q1.x);
    a1 = a1 * sc + p1 * bfhi(q1.x);
    a2 = a2 * sc + p1 * bflo(q1.y);
    a3 = a3 * sc + p1 * bfhi(q1.y);
    m = mn;
  }

  float inv = 1.f / (ssum + 1e-16f);
  size_t o = (size_t)n * DD + lane * 4;
  float4 xb = *reinterpret_cast<const float4*>(x + o);
  float4 bb = *reinterpret_cast<const float4*>(bias + lane * 4);
  float4 res;
  res.x = xb.x + bb.x + a0 * inv;
  res.y = xb.y + bb.y + a1 * inv;
  res.z = xb.z + bb.z + a2 * inv;
  res.w = xb.w + bb.w + a3 * inv;
  *reinterpret_cast<float4*>(out + o) = res;

  // per-edge alpha in original edge order
  for (int t = lane; t < cnt; t += 32)
    alpha[rec_eid[base + t]] = __expf(rec_logit[base + t] - m) * inv;
}

extern "C" void kernel_launch(void* const* d_in, const int* in_sizes, int n_in,
                              void* d_out, int out_size, void* d_ws, size_t ws_size,
                              hipStream_t stream) {
  const float* x    = (const float*)d_in[0];
  const int*   ei   = (const int*)d_in[1];
  const int*   et   = (const int*)d_in[2];
  const float* W    = (const float*)d_in[3];
  const float* qv   = (const float*)d_in[4];
  const float* kv   = (const float*)d_in[5];
  const float* bias = (const float*)d_in[6];

  float* out   = (float*)d_out;              // [NN*DD]
  float* alpha = out + (size_t)NN * DD;      // [NE]

  char* p = (char*)d_ws;
  bf16*  hx        = (bf16*)p;        p += (size_t)RR * NN * DD * sizeof(bf16); // 76.8 MB
  float* nq        = (float*)p;       p += (size_t)RR * NN * sizeof(float);
  float* nk        = (float*)p;       p += (size_t)RR * NN * sizeof(float);
  float* wq        = (float*)p;       p += RR * DD * sizeof(float);
  float* wk        = (float*)p;       p += RR * DD * sizeof(float);
  int*   deg       = (int*)p;         p += NN * sizeof(int);
  int*   offs      = (int*)p;         p += NN * sizeof(int);
  int*   cur       = (int*)p;         p += NN * sizeof(int);
  int*   rec_src   = (int*)p;         p += (size_t)NE * sizeof(int);
  int*   rec_eid   = (int*)p;         p += (size_t)NE * sizeof(int);
  float* rec_logit = (float*)p;       p += (size_t)NE * sizeof(float);

  k_init<<<(NN + 255) / 256, 256, 0, stream>>>(deg, cur);
  k_wqk<<<(RR * DD + 255) / 256, 256, 0, stream>>>(W, qv, kv, wq, wk);
  k_gemm<<<dim3((NN + BM - 1) / BM, RR), 256, 0, stream>>>(x, W, hx);
  k_nqk<<<(NN + 3) / 4, 256, 0, stream>>>(x, wq, wk, nq, nk);
  k_hist<<<(NE + 255) / 256, 256, 0, stream>>>(ei, deg);
  k_scan<<<1, 1024, 0, stream>>>(deg, offs);
  k_place<<<(NE + 255) / 256, 256, 0, stream>>>(ei, et, nq, nk, offs, cur,
                                                rec_src, rec_eid, rec_logit);
  k_agg<<<(NN + 7) / 8, 256, 0, stream>>>(x, bias, offs, deg, rec_src, rec_eid,
                                          rec_logit, hx, out, alpha);
}

// Round 3
// 363.084 us; speedup vs baseline: 6.4147x; 1.2332x over previous
//
#include <hip/hip_runtime.h>
#include <hip/hip_bf16.h>
#include <cstdint>

#define NN 50000
#define NE 1200000
#define DD 128
#define RR 6
#define NEG 0.2f

typedef __hip_bfloat16 bf16;
typedef __attribute__((ext_vector_type(8))) short short8;
typedef __attribute__((ext_vector_type(4))) float f32x4;

__device__ __forceinline__ float bflo(unsigned u) { return __uint_as_float((u & 0xFFFFu) << 16); }
__device__ __forceinline__ float bfhi(unsigned u) { return __uint_as_float(u & 0xFFFF0000u); }
__device__ __forceinline__ ushort f2b(float v) {  // f32 -> bf16 RTNE
  unsigned b = __float_as_uint(v);
  return (ushort)((b + 0x7FFFu + ((b >> 16) & 1u)) >> 16);
}

// ---------------- init: zero degree + cursor ------------------------------
__global__ __launch_bounds__(256) void k_init(int* __restrict__ deg,
                                              int* __restrict__ cur) {
  int idx = blockIdx.x * 256 + threadIdx.x;
  if (idx < NN) { deg[idx] = 0; cur[idx] = 0; }
}

// ---------------- wq[r,d] = sum_o W[r,d,o] q[o]; same for k ---------------
__global__ __launch_bounds__(256) void k_wqk(const float* __restrict__ W,
    const float* __restrict__ qv, const float* __restrict__ kv,
    float* __restrict__ wq, float* __restrict__ wk) {
  int t = blockIdx.x * 256 + threadIdx.x;
  if (t >= RR * DD) return;
  int r = t / DD, d = t % DD;
  const float* row = W + ((size_t)r * DD + d) * DD;
  float aq = 0.f, ak = 0.f;
  for (int o = 0; o < DD; ++o) { float w = row[o]; aq += w * qv[o]; ak += w * kv[o]; }
  wq[t] = aq; wk[t] = ak;
}

// ---------------- nq[r,n] = x[n]·wq[r], one wave per node -----------------
__global__ __launch_bounds__(256) void k_nqk(const float* __restrict__ x,
    const float* __restrict__ wq, const float* __restrict__ wk,
    float* __restrict__ nq, float* __restrict__ nk) {
  int w = threadIdx.x >> 6, lane = threadIdx.x & 63;
  int n = blockIdx.x * 4 + w;
  if (n >= NN) return;
  float x0 = x[(size_t)n * DD + lane];
  float x1 = x[(size_t)n * DD + 64 + lane];
  for (int r = 0; r < RR; ++r) {
    float pq = x0 * wq[r * DD + lane] + x1 * wq[r * DD + 64 + lane];
    float pk = x0 * wk[r * DD + lane] + x1 * wk[r * DD + 64 + lane];
    #pragma unroll
    for (int m = 32; m > 0; m >>= 1) { pq += __shfl_xor(pq, m); pk += __shfl_xor(pk, m); }
    if (lane == 0) { nq[r * NN + n] = pq; nk[r * NN + n] = pk; }
  }
}

// ---------------- pack W into MFMA B-fragment order (bf16) ----------------
// wp[((r*8+cf)*4+ks)*64 + lane][e] = W_r[k = ks*32 + 8*(lane>>4)+e][col = cf*16 + (lane&15)]
__global__ __launch_bounds__(256) void k_wpack(const float* __restrict__ W,
                                               ushort* __restrict__ wp) {
  int t = blockIdx.x * 256 + threadIdx.x;
  if (t >= RR * 8 * 4 * 64) return;
  int lane = t & 63;
  int ks = (t >> 6) & 3;
  int cf = (t >> 8) & 7;
  int r = t >> 11;
  int col = cf * 16 + (lane & 15);
  int k0 = ks * 32 + (lane >> 4) * 8;
  ushort* dst = wp + (size_t)t * 8;
  #pragma unroll
  for (int e = 0; e < 8; ++e)
    dst[e] = f2b(W[((size_t)r * DD + (k0 + e)) * DD + col]);
}

// ---------------- hx[r,n,o] via bf16 MFMA; A regs reused over relations ---
__global__ __launch_bounds__(256) void k_gemm(const float* __restrict__ x,
    const ushort* __restrict__ wp, ushort* __restrict__ hx) {
  int tid = threadIdx.x;
  int w = tid >> 6, l = tid & 63;
  int wrow = w & 1, wcol = w >> 1;
  int row0 = blockIdx.x * 64 + wrow * 32;
  int lr = l & 15, lg = l >> 4;

  // A fragments: rows row0 + rf*16 + lr, k = ks*32 + lg*8 + e  (cvt f32->bf16)
  short8 af[2][4];
  #pragma unroll
  for (int rf = 0; rf < 2; ++rf) {
    int row = row0 + rf * 16 + lr;
    row = row < NN ? row : NN - 1;
    const float* src = x + (size_t)row * DD + lg * 8;
    #pragma unroll
    for (int ks = 0; ks < 4; ++ks) {
      float4 u0 = *reinterpret_cast<const float4*>(src + ks * 32);
      float4 u1 = *reinterpret_cast<const float4*>(src + ks * 32 + 4);
      short8 a;
      a[0] = (short)f2b(u0.x); a[1] = (short)f2b(u0.y);
      a[2] = (short)f2b(u0.z); a[3] = (short)f2b(u0.w);
      a[4] = (short)f2b(u1.x); a[5] = (short)f2b(u1.y);
      a[6] = (short)f2b(u1.z); a[7] = (short)f2b(u1.w);
      af[rf][ks] = a;
    }
  }

  for (int r = 0; r < RR; ++r) {
    #pragma unroll
    for (int cfl = 0; cfl < 4; ++cfl) {
      int cfg = wcol * 4 + cfl;
      const ushort* bp = wp + (((size_t)(r * 8 + cfg) * 4) * 64 + l) * 8;
      short8 b0 = *reinterpret_cast<const short8*>(bp);
      short8 b1 = *reinterpret_cast<const short8*>(bp + 512);
      short8 b2 = *reinterpret_cast<const short8*>(bp + 1024);
      short8 b3 = *reinterpret_cast<const short8*>(bp + 1536);
      f32x4 acc0 = {0.f, 0.f, 0.f, 0.f};
      f32x4 acc1 = {0.f, 0.f, 0.f, 0.f};
      acc0 = __builtin_amdgcn_mfma_f32_16x16x32_bf16(af[0][0], b0, acc0, 0, 0, 0);
      acc1 = __builtin_amdgcn_mfma_f32_16x16x32_bf16(af[1][0], b0, acc1, 0, 0, 0);
      acc0 = __builtin_amdgcn_mfma_f32_16x16x32_bf16(af[0][1], b1, acc0, 0, 0, 0);
      acc1 = __builtin_amdgcn_mfma_f32_16x16x32_bf16(af[1][1], b1, acc1, 0, 0, 0);
      acc0 = __builtin_amdgcn_mfma_f32_16x16x32_bf16(af[0][2], b2, acc0, 0, 0, 0);
      acc1 = __builtin_amdgcn_mfma_f32_16x16x32_bf16(af[1][2], b2, acc1, 0, 0, 0);
      acc0 = __builtin_amdgcn_mfma_f32_16x16x32_bf16(af[0][3], b3, acc0, 0, 0, 0);
      acc1 = __builtin_amdgcn_mfma_f32_16x16x32_bf16(af[1][3], b3, acc1, 0, 0, 0);

      int col = cfg * 16 + lr;
      #pragma unroll
      for (int rf = 0; rf < 2; ++rf) {
        int rowb = row0 + rf * 16 + lg * 4;
        f32x4 ac = rf ? acc1 : acc0;
        #pragma unroll
        for (int j = 0; j < 4; ++j) {
          int rowz = rowb + j;
          if (rowz < NN)
            hx[((size_t)r * NN + rowz) * DD + col] = f2b(ac[j]);
        }
      }
    }
  }
}

// ---------------- histogram of destinations -------------------------------
__global__ __launch_bounds__(256) void k_hist(const int* __restrict__ ei,
                                              int* __restrict__ deg) {
  int e = blockIdx.x * 256 + threadIdx.x;
  if (e >= NE) return;
  atomicAdd(&deg[ei[NE + e]], 1);
}

// ---------------- exclusive scan (single block) ----------------------------
__global__ __launch_bounds__(1024) void k_scan(const int* __restrict__ deg,
                                               int* __restrict__ offs) {
  __shared__ int part[1024];
  int t = threadIdx.x;
  const int C = (NN + 1023) / 1024;
  int lo = t * C, hi = lo + C < NN ? lo + C : NN;
  int sum = 0;
  for (int i = lo; i < hi; ++i) sum += deg[i];
  part[t] = sum;
  __syncthreads();
  for (int off = 1; off < 1024; off <<= 1) {
    int u = (t >= off) ? part[t - off] : 0;
    __syncthreads();
    part[t] += u;
    __syncthreads();
  }
  int run = part[t] - sum;
  for (int i = lo; i < hi; ++i) { offs[i] = run; run += deg[i]; }
}

// ---------------- place edges into CSR slots, precompute logits ------------
__global__ __launch_bounds__(256) void k_place(const int* __restrict__ ei,
    const int* __restrict__ et, const float* __restrict__ nq,
    const float* __restrict__ nk, const int* __restrict__ offs,
    int* __restrict__ cur, int* __restrict__ rec_src,
    int* __restrict__ rec_eid, float* __restrict__ rec_logit) {
  int e = blockIdx.x * 256 + threadIdx.x;
  if (e >= NE) return;
  int s = ei[e], d = ei[NE + e], r = et[e];
  float l = nq[r * NN + d] + nk[r * NN + s];
  l = l > 0.f ? l : NEG * l;
  int pos = offs[d] + atomicAdd(&cur[d], 1);
  rec_src[pos] = s | (r << 20);
  rec_eid[pos] = e;
  rec_logit[pos] = l;
}

// ---------------- fused online-softmax gather-aggregate --------------------
__global__ __launch_bounds__(256) void k_agg(const float* __restrict__ x,
    const float* __restrict__ bias, const int* __restrict__ offs,
    const int* __restrict__ deg, const int* __restrict__ rec_src,
    const int* __restrict__ rec_eid, const float* __restrict__ rec_logit,
    const bf16* __restrict__ hx, float* __restrict__ out,
    float* __restrict__ alpha) {
  int g = threadIdx.x >> 5, lane = threadIdx.x & 31;
  int n = blockIdx.x * 8 + g;
  if (n >= NN) return;
  int base = offs[n], cnt = deg[n];

  float m = -1e30f, ssum = 0.f;
  float a0 = 0.f, a1 = 0.f, a2 = 0.f, a3 = 0.f;

  int j = 0;
  for (; j + 1 < cnt; j += 2) {
    int sr1 = rec_src[base + j], sr2 = rec_src[base + j + 1];
    float l1 = rec_logit[base + j], l2 = rec_logit[base + j + 1];
    const bf16* row1 = hx + ((size_t)(sr1 >> 20) * NN + (sr1 & 0xFFFFF)) * DD + lane * 4;
    const bf16* row2 = hx + ((size_t)(sr2 >> 20) * NN + (sr2 & 0xFFFFF)) * DD + lane * 4;
    uint2 q1 = *reinterpret_cast<const uint2*>(row1);
    uint2 q2 = *reinterpret_cast<const uint2*>(row2);
    float mn = fmaxf(m, fmaxf(l1, l2));
    float sc = __expf(m - mn);
    float p1 = __expf(l1 - mn), p2 = __expf(l2 - mn);
    ssum = ssum * sc + p1 + p2;
    a0 = a0 * sc + p1 * bflo(q1.x) + p2 * bflo(q2.x);
    a1 = a1 * sc + p1 * bfhi(q1.x) + p2 * bfhi(q2.x);
    a2 = a2 * sc + p1 * bflo(q1.y) + p2 * bflo(q2.y);
    a3 = a3 * sc + p1 * bfhi(q1.y) + p2 * bfhi(q2.y);
    m = mn;
  }
  if (j < cnt) {
    int sr1 = rec_src[base + j];
    float l1 = rec_logit[base + j];
    const bf16* row1 = hx + ((size_t)(sr1 >> 20) * NN + (sr1 & 0xFFFFF)) * DD + lane * 4;
    uint2 q1 = *reinterpret_cast<const uint2*>(row1);
    float mn = fmaxf(m, l1);
    float sc = __expf(m - mn);
    float p1 = __expf(l1 - mn);
    ssum = ssum * sc + p1;
    a0 = a0 * sc + p1 * bflo(q1.x);
    a1 = a1 * sc + p1 * bfhi(q1.x);
    a2 = a2 * sc + p1 * bflo(q1.y);
    a3 = a3 * sc + p1 * bfhi(q1.y);
    m = mn;
  }

  float inv = 1.f / (ssum + 1e-16f);
  size_t o = (size_t)n * DD + lane * 4;
  float4 xb = *reinterpret_cast<const float4*>(x + o);
  float4 bb = *reinterpret_cast<const float4*>(bias + lane * 4);
  float4 res;
  res.x = xb.x + bb.x + a0 * inv;
  res.y = xb.y + bb.y + a1 * inv;
  res.z = xb.z + bb.z + a2 * inv;
  res.w = xb.w + bb.w + a3 * inv;
  *reinterpret_cast<float4*>(out + o) = res;

  for (int t = lane; t < cnt; t += 32)
    alpha[rec_eid[base + t]] = __expf(rec_logit[base + t] - m) * inv;
}

extern "C" void kernel_launch(void* const* d_in, const int* in_sizes, int n_in,
                              void* d_out, int out_size, void* d_ws, size_t ws_size,
                              hipStream_t stream) {
  const float* x    = (const float*)d_in[0];
  const int*   ei   = (const int*)d_in[1];
  const int*   et   = (const int*)d_in[2];
  const float* W    = (const float*)d_in[3];
  const float* qv   = (const float*)d_in[4];
  const float* kv   = (const float*)d_in[5];
  const float* bias = (const float*)d_in[6];

  float* out   = (float*)d_out;              // [NN*DD]
  float* alpha = out + (size_t)NN * DD;      // [NE]

  char* p = (char*)d_ws;
  bf16*  hx        = (bf16*)p;        p += (size_t)RR * NN * DD * sizeof(bf16); // 76.8 MB
  float* nq        = (float*)p;       p += (size_t)RR * NN * sizeof(float);
  float* nk        = (float*)p;       p += (size_t)RR * NN * sizeof(float);
  float* wq        = (float*)p;       p += RR * DD * sizeof(float);
  float* wk        = (float*)p;       p += RR * DD * sizeof(float);
  int*   deg       = (int*)p;         p += NN * sizeof(int);
  int*   offs      = (int*)p;         p += NN * sizeof(int);
  int*   cur       = (int*)p;         p += NN * sizeof(int);
  int*   rec_src   = (int*)p;         p += (size_t)NE * sizeof(int);
  int*   rec_eid   = (int*)p;         p += (size_t)NE * sizeof(int);
  float* rec_logit = (float*)p;       p += (size_t)NE * sizeof(float);
  ushort* wp       = (ushort*)p;      p += (size_t)RR * 8 * 4 * 64 * 8 * sizeof(ushort); // 197 KB

  k_init<<<(NN + 255) / 256, 256, 0, stream>>>(deg, cur);
  k_wqk<<<(RR * DD + 255) / 256, 256, 0, stream>>>(W, qv, kv, wq, wk);
  k_wpack<<<(RR * 8 * 4 * 64 + 255) / 256, 256, 0, stream>>>(W, wp);
  k_gemm<<<(NN + 63) / 64, 256, 0, stream>>>(x, wp, (ushort*)hx);
  k_nqk<<<(NN + 3) / 4, 256, 0, stream>>>(x, wq, wk, nq, nk);
  k_hist<<<(NE + 255) / 256, 256, 0, stream>>>(ei, deg);
  k_scan<<<1, 1024, 0, stream>>>(deg, offs);
  k_place<<<(NE + 255) / 256, 256, 0, stream>>>(ei, et, nq, nk, offs, cur,
                                                rec_src, rec_eid, rec_logit);
  k_agg<<<(NN + 7) / 8, 256, 0, stream>>>(x, bias, offs, deg, rec_src, rec_eid,
                                          rec_logit, hx, out, alpha);
}